// Round 11
// baseline (258.044 us; speedup 1.0000x reference)
//
#include <hip/hip_runtime.h>
#include <hip/hip_bf16.h>

#define SQL 2048
#define SKL 2048
#define HH  1024
#define NHH 16
#define HDD 64
#define BB  2
#define MM  (BB*SQL)   // 4096 tokens

typedef __attribute__((ext_vector_type(8))) short short8;
typedef __attribute__((ext_vector_type(4))) short short4v;
typedef __attribute__((ext_vector_type(4))) float f32x4;
typedef unsigned short u16;

__device__ inline u16 f2bf(float f) {
    unsigned int u = __float_as_uint(f);
    u += 0x7fffu + ((u >> 16) & 1u);   // RNE
    return (u16)(u >> 16);
}

// pair-convert: compiler emits v_cvt_pk_bf16_f32 (intrinsic, NOT inline asm — m240)
__device__ inline unsigned int bf2_bits(float a, float b) {
    __hip_bfloat162 h = __float22bfloat162_rn(make_float2(a, b));
    unsigned int r;
    __builtin_memcpy(&r, &h, 4);
    return r;
}

__device__ inline void gl_lds16(const void* g, void* l) {
    __builtin_amdgcn_global_load_lds(
        (const __attribute__((address_space(1))) unsigned int*)g,
        (__attribute__((address_space(3))) unsigned int*)l, 16, 0, 0);
}

// ---------------- fp32 -> bf16 convert, WEIGHTS ONLY (4 MB; activations fused into proj) ----
__global__ __launch_bounds__(256) void cvt_w_kernel(
    const float* __restrict__ wq, const float* __restrict__ wk,
    const float* __restrict__ wv, const float* __restrict__ wo,
    u16* __restrict__ wqb, u16* __restrict__ wkb, u16* __restrict__ wvb, u16* __restrict__ wob)
{
    int b = blockIdx.x;
    const float* src; u16* dst;
    if      (b < 1024) { src = wq; dst = wqb; }
    else if (b < 2048) { src = wk; dst = wkb; b -= 1024; }
    else if (b < 3072) { src = wv; dst = wvb; b -= 2048; }
    else               { src = wo; dst = wob; b -= 3072; }
    int i = (b * 256 + threadIdx.x) * 4;
    float4 vv = *(const float4*)(src + i);
    ushort4 oo;
    oo.x = f2bf(vv.x); oo.y = f2bf(vv.y); oo.z = f2bf(vv.z); oo.w = f2bf(vv.w);
    *(ushort4*)(dst + i) = oo;
}

// ---------------- fused q/k/v projection: C = A_f32 @ W^T (+bias) ----------------
// grid.z in {0:q, 1:k, 2:v}. 128x128 tile, BK=64 (R4: fewer drains = -9%).
// R11: A read DIRECTLY as fp32 (original inputs) with reg-staged fp32->bf16
// conversion into the same XOR-swizzled LDS layout (per-lane ds_write_b128
// gives full dst flexibility). Kills the activation cvt pass entirely.
// W via global_load_lds from pre-converted bf16 (cvt_w).
// R8-WIN epilogue: coalesced stores via per-wave LDS transpose scratch.
__global__ __launch_bounds__(256) void proj_kernel(
    const float* __restrict__ qf, const float* __restrict__ kf, const float* __restrict__ vf,
    const u16* __restrict__ wqb, const u16* __restrict__ wkb, const u16* __restrict__ wvb,
    const float* __restrict__ bq, const float* __restrict__ bk, const float* __restrict__ bv,
    u16* __restrict__ oq, u16* __restrict__ ok, u16* __restrict__ ov)
{
    const int z = blockIdx.z;
    const float* A    = (z == 0) ? qf  : (z == 1) ? kf  : vf;
    const u16* W      = (z == 0) ? wqb : (z == 1) ? wkb : wvb;
    const float* bias = (z == 0) ? bq  : (z == 1) ? bk  : bv;
    u16* outb         = (z == 0) ? oq  : (z == 1) ? ok  : ov;
    const float scale = (z == 0) ? 0.125f * 1.4426950408889634f : 1.0f;

    __shared__ u16 pool[2 * 128 * 64];   // K-loop: A tile | W tile; epilogue: 4x8KB wave scratch
    u16* lds_a = pool;
    u16* lds_b = pool + 128 * 64;

    const int t = threadIdx.x;
    const int lane = t & 63;
    const int quad = lane >> 4;
    const int lo = lane & 15;
    const int wv = t >> 6;
    const int wm = (wv >> 1) * 64, wn = (wv & 1) * 64;
    const int m0 = blockIdx.x * 128;
    const int n0 = blockIdx.y * 128;

    f32x4 acc[4][4];
#pragma unroll
    for (int i = 0; i < 4; i++)
#pragma unroll
        for (int j = 0; j < 4; j++) acc[i][j] = (f32x4){0.f, 0.f, 0.f, 0.f};

    // staging: 4 slots/thread/matrix; slot s = row s>>3, chunk-slot s&7
    // holds global chunk (s&7)^(row&7)
    int rr[4], cc[4];
#pragma unroll
    for (int u = 0; u < 4; u++) {
        int sl = u * 256 + t;
        rr[u] = sl >> 3;
        cc[u] = ((sl & 7) ^ (rr[u] & 7)) * 8;
    }

    for (int k0 = 0; k0 < HH; k0 += 64) {
        // issue all A fp32 loads + W DMA first (ILP), then convert+write
        float4 a0[4], a1[4];
#pragma unroll
        for (int u = 0; u < 4; u++) {
            const float* src = A + (size_t)(m0 + rr[u]) * HH + k0 + cc[u];
            a0[u] = *(const float4*)src;
            a1[u] = *(const float4*)(src + 4);
            gl_lds16(W + (size_t)(n0 + rr[u]) * HH + k0 + cc[u], &lds_b[(u * 256 + t) * 8]);
        }
#pragma unroll
        for (int u = 0; u < 4; u++) {
            uint4 pk;
            pk.x = bf2_bits(a0[u].x, a0[u].y);
            pk.y = bf2_bits(a0[u].z, a0[u].w);
            pk.z = bf2_bits(a1[u].x, a1[u].y);
            pk.w = bf2_bits(a1[u].z, a1[u].w);
            *(uint4*)&lds_a[(u * 256 + t) * 8] = pk;
        }
        __syncthreads();   // drains vmcnt (A loads + W DMA) and lgkm (ds_writes)
#pragma unroll
        for (int kk = 0; kk < 2; kk++) {
            short8 af[4], bf[4];
#pragma unroll
            for (int i = 0; i < 4; i++) {
                const int ra = wm + i * 16 + lo;
                const int rb = wn + i * 16 + lo;
                af[i] = *(const short8*)&lds_a[ra * 64 + (((kk * 4 + quad) ^ (ra & 7)) * 8)];
                bf[i] = *(const short8*)&lds_b[rb * 64 + (((kk * 4 + quad) ^ (rb & 7)) * 8)];
            }
            if (z == 2) {   // wave-uniform: C rows = tokens, cols = dims
#pragma unroll
                for (int i = 0; i < 4; i++)
#pragma unroll
                    for (int j = 0; j < 4; j++)
                        acc[i][j] = __builtin_amdgcn_mfma_f32_16x16x32_bf16(af[i], bf[j], acc[i][j], 0, 0, 0);
            } else {        // C rows = dims, cols = tokens
#pragma unroll
                for (int i = 0; i < 4; i++)
#pragma unroll
                    for (int j = 0; j < 4; j++)
                        acc[i][j] = __builtin_amdgcn_mfma_f32_16x16x32_bf16(bf[j], af[i], acc[i][j], 0, 0, 0);
            }
        }
        __syncthreads();   // all reads done before next stage / epilogue reuse
    }

    u16* cbuf = &pool[wv * 4096];   // per-wave 64x64 bf16 scratch, stride 64 u16

    if (z != 2) {
        // C^T: lane holds (d_local = wn-rel j*16+quad*4+r, tok_local = i*16+lo).
#pragma unroll
        for (int j = 0; j < 4; j++) {
            float4 b4 = *(const float4*)&bias[n0 + wn + j * 16 + quad * 4];
#pragma unroll
            for (int i = 0; i < 4; i++) {
                int tokl = i * 16 + lo;
                int lc = j * 2 + (quad >> 1);
                int phys = lc ^ (tokl & 7);
                uint2 pk;
                pk.x = bf2_bits((acc[i][j][0] + b4.x) * scale, (acc[i][j][1] + b4.y) * scale);
                pk.y = bf2_bits((acc[i][j][2] + b4.z) * scale, (acc[i][j][3] + b4.w) * scale);
                *(uint2*)&cbuf[tokl * 64 + phys * 8 + (quad & 1) * 4] = pk;
            }
        }
        __syncthreads();
#pragma unroll
        for (int it = 0; it < 8; it++) {
            int row = it * 8 + (lane >> 3);          // tok_local
            int lc2 = lane & 7;                      // d chunk
            short8 val = *(const short8*)&cbuf[row * 64 + ((lc2 ^ (row & 7)) * 8)];
            int tok = m0 + wm + row;
            int dgb = n0 + wn + lc2 * 8;
            int bi = tok >> 11, s = tok & 2047;
            int head = dgb >> 6, d = dgb & 63;
            *(short8*)&outb[(((size_t)bi * NHH + head) * SQL + s) * HDD + d] = val;
        }
    } else {
        // C: lane holds (tok_local = i*16+quad*4+r, d_local = j*16+lo).
#pragma unroll
        for (int j = 0; j < 4; j++) {
            float bsc = bias[n0 + wn + j * 16 + lo];
#pragma unroll
            for (int i = 0; i < 4; i++) {
                int dgl = j * 16 + lo;
                int lc = i * 2 + (quad >> 1);
                int phys = lc ^ (dgl & 7);
                uint2 pk;
                pk.x = bf2_bits(acc[i][j][0] + bsc, acc[i][j][1] + bsc);
                pk.y = bf2_bits(acc[i][j][2] + bsc, acc[i][j][3] + bsc);
                *(uint2*)&cbuf[dgl * 64 + phys * 8 + (quad & 1) * 4] = pk;
            }
        }
        __syncthreads();
#pragma unroll
        for (int it = 0; it < 8; it++) {
            int row = it * 8 + (lane >> 3);          // d_local
            int lc2 = lane & 7;                      // tok chunk
            short8 val = *(const short8*)&cbuf[row * 64 + ((lc2 ^ (row & 7)) * 8)];
            int dg = n0 + wn + row;
            int tokb = m0 + wm + lc2 * 8;
            int bi = tokb >> 11, s = tokb & 2047;
            int head = dg >> 6, d = dg & 63;
            *(short8*)&outb[(((size_t)bi * NHH + head) * HDD + d) * SKL + s] = val;
        }
    }
}

// ---------------- out-projection: fp32 [tok][col] = A@Wo^T + bias + resid ----------------
// R11: BM=64 tiles -> grid (64,8) = 512 blocks = 2/CU (R4 occupancy lever;
// was 256 blocks = 1/CU, fully exposed drains). Waves 2x2 of 32x64, acc[2][4].
// Swapped mfma + single-pass coalesced fp32 epilogue (wave-private scratch).
__global__ __launch_bounds__(256) void outproj_kernel(
    const u16* __restrict__ A, const u16* __restrict__ W,
    const float* __restrict__ bias, const float* __restrict__ resid,
    float* __restrict__ outf)
{
    __shared__ u16 pool[2 * 128 * 64];   // K-loop: A 8KB | W 16KB; epilogue: 4x8KB wave scratch
    u16* lds_a = pool;
    u16* lds_b = pool + 64 * 64;

    const int t = threadIdx.x;
    const int lane = t & 63;
    const int quad = lane >> 4;
    const int lo = lane & 15;
    const int wv = t >> 6;
    const int wm = (wv >> 1) * 32, wn = (wv & 1) * 64;
    const int m0 = blockIdx.x * 64;
    const int n0 = blockIdx.y * 128;

    f32x4 acc[2][4];
#pragma unroll
    for (int i = 0; i < 2; i++)
#pragma unroll
        for (int j = 0; j < 4; j++) acc[i][j] = (f32x4){0.f, 0.f, 0.f, 0.f};

    int rr[4], cc[4];
#pragma unroll
    for (int u = 0; u < 4; u++) {
        int sl = u * 256 + t;
        rr[u] = sl >> 3;
        cc[u] = ((sl & 7) ^ (rr[u] & 7)) * 8;
    }

    for (int k0 = 0; k0 < HH; k0 += 64) {
#pragma unroll
        for (int u = 0; u < 2; u++)   // A: 64 rows -> 2 slots/thread
            gl_lds16(A + (size_t)(m0 + rr[u]) * HH + k0 + cc[u], &lds_a[(u * 256 + t) * 8]);
#pragma unroll
        for (int u = 0; u < 4; u++)   // W: 128 rows -> 4 slots/thread
            gl_lds16(W + (size_t)(n0 + rr[u]) * HH + k0 + cc[u], &lds_b[(u * 256 + t) * 8]);
        __syncthreads();
#pragma unroll
        for (int kk = 0; kk < 2; kk++) {
            short8 af[2], bf[4];
#pragma unroll
            for (int i = 0; i < 2; i++) {
                const int ra = wm + i * 16 + lo;
                af[i] = *(const short8*)&lds_a[ra * 64 + (((kk * 4 + quad) ^ (ra & 7)) * 8)];
            }
#pragma unroll
            for (int j = 0; j < 4; j++) {
                const int rb = wn + j * 16 + lo;
                bf[j] = *(const short8*)&lds_b[rb * 64 + (((kk * 4 + quad) ^ (rb & 7)) * 8)];
            }
#pragma unroll
            for (int i = 0; i < 2; i++)
#pragma unroll
                for (int j = 0; j < 4; j++)
                    acc[i][j] = __builtin_amdgcn_mfma_f32_16x16x32_bf16(bf[j], af[i], acc[i][j], 0, 0, 0);
        }
        __syncthreads();
    }

    // epilogue: lane holds (col_local = j*16+quad*4+r, tok_local = i*16+lo).
    // Stage [32 tok][64 col] f32 into wave-private scratch, read back coalesced.
    float* cbuf = (float*)&pool[wv * 4096];   // 8KB per wave
#pragma unroll
    for (int j = 0; j < 4; j++) {
        float4 b4 = *(const float4*)&bias[n0 + wn + j * 16 + quad * 4];
#pragma unroll
        for (int i = 0; i < 2; i++) {
            int tl = i * 16 + lo;                // 0..31
            int lc = j * 4 + quad;               // 16B chunk (4 f32), 0..15
            int phys = lc ^ (tl & 7);
            f32x4 vq;
            vq[0] = acc[i][j][0] + b4.x; vq[1] = acc[i][j][1] + b4.y;
            vq[2] = acc[i][j][2] + b4.z; vq[3] = acc[i][j][3] + b4.w;
            *(f32x4*)&cbuf[tl * 64 + phys * 4] = vq;
        }
    }
    // wave-private scratch: same-wave ds_write -> ds_read ordered via lgkmcnt
#pragma unroll
    for (int it = 0; it < 8; it++) {
        int rowl = it * 4 + (lane >> 4);         // 0..31
        int lc2 = lane & 15;
        f32x4 val = *(const f32x4*)&cbuf[rowl * 64 + ((lc2 ^ (rowl & 7)) * 4)];
        int tok = m0 + wm + rowl;
        int col = n0 + wn + lc2 * 4;
        const float4 rd = *(const float4*)&resid[(size_t)tok * HH + col];
        float4 o;
        o.x = val[0] + rd.x; o.y = val[1] + rd.y;
        o.z = val[2] + rd.z; o.w = val[3] + rd.w;
        *(float4*)&outf[(size_t)tok * HH + col] = o;
    }
}

// ---------------- Flash attention (S^T orientation) — R8 verbatim (best: 49.4 µs) --------
// R9 (cvt_pk/defer-max/setprio) and R10 (LDS-staged O epilogue) both A/B-regressed:
// the per-tile chain is latency-bound; removed VALU was idle-cycle filler.
#define PSTR 72   // [16 q][64 key] P tile row stride (u16): 144 B = 16B-aligned, bank-spread

__global__ __launch_bounds__(256) void attn_kernel(
    const u16* __restrict__ qb, const u16* __restrict__ kb, const u16* __restrict__ vtb,
    u16* __restrict__ attn_out)
{
    __shared__ u16 k_lds[64 * 64];
    __shared__ u16 vt_lds[64 * 64];
    __shared__ u16 p_lds[4 * 16 * PSTR];

    const int t = threadIdx.x;
    const int lane = t & 63;
    const int quad = lane >> 4;
    const int lo = lane & 15;
    const int w = t >> 6;
    const int qt = (SQL / 64 - 1) - (blockIdx.x >> 5);  // heavy q-tiles first
    const int bh = blockIdx.x & 31;
    const int q0 = qt * 64;

    const u16* qbase = qb + ((size_t)bh * SQL + q0 + w * 16 + lo) * HDD + quad * 8;
    short8 qf0 = *(const short8*)qbase;
    short8 qf1 = *(const short8*)(qbase + 32);

    float m_s = -__builtin_inff(), l_s = 0.f;
    f32x4 o[4];
#pragma unroll
    for (int j = 0; j < 4; j++) o[j] = (f32x4){0.f, 0.f, 0.f, 0.f};

    const int sl0 = t, sl1 = 256 + t;
    const int r0 = sl0 >> 3, c0 = ((sl0 & 7) ^ (r0 & 7)) * 8;
    const int r1 = sl1 >> 3, c1 = ((sl1 & 7) ^ (r1 & 7)) * 8;
    const u16* kbh = kb + (size_t)bh * SKL * HDD;
    const u16* vbh = vtb + (size_t)bh * HDD * SKL;
    u16* ppriv = &p_lds[w * 16 * PSTR];

    for (int kt = 0; kt <= qt; kt++) {
        const int k0 = kt * 64;
        gl_lds16(kbh + (size_t)(k0 + r0) * HDD + c0, &k_lds[sl0 * 8]);
        gl_lds16(kbh + (size_t)(k0 + r1) * HDD + c1, &k_lds[sl1 * 8]);
        gl_lds16(vbh + (size_t)r0 * SKL + k0 + c0, &vt_lds[sl0 * 8]);
        gl_lds16(vbh + (size_t)r1 * SKL + k0 + c1, &vt_lds[sl1 * 8]);
        __syncthreads();

        f32x4 s[4];
#pragma unroll
        for (int nt = 0; nt < 4; nt++) {
            const int row = nt * 16 + lo;
            short8 kf0 = *(const short8*)&k_lds[row * 64 + ((quad ^ (row & 7)) * 8)];
            short8 kf1 = *(const short8*)&k_lds[row * 64 + (((4 + quad) ^ (row & 7)) * 8)];
            s[nt] = (f32x4){0.f, 0.f, 0.f, 0.f};
            s[nt] = __builtin_amdgcn_mfma_f32_16x16x32_bf16(kf0, qf0, s[nt], 0, 0, 0);
            s[nt] = __builtin_amdgcn_mfma_f32_16x16x32_bf16(kf1, qf1, s[nt], 0, 0, 0);
        }
        if (kt == qt) {
            const int ql = w * 16 + lo;
#pragma unroll
            for (int nt = 0; nt < 4; nt++)
#pragma unroll
                for (int r = 0; r < 4; r++)
                    if (nt * 16 + quad * 4 + r > ql) s[nt][r] = -__builtin_inff();
        }

        float mx = s[0][0];
#pragma unroll
        for (int nt = 0; nt < 4; nt++)
#pragma unroll
            for (int r = 0; r < 4; r++) mx = fmaxf(mx, s[nt][r]);
        mx = fmaxf(mx, __shfl_xor(mx, 16));
        mx = fmaxf(mx, __shfl_xor(mx, 32));
        float mnew = fmaxf(m_s, mx);
        float al = __builtin_amdgcn_exp2f(m_s - mnew);
        m_s = mnew;
        float rs = 0.f;
#pragma unroll
        for (int nt = 0; nt < 4; nt++)
#pragma unroll
            for (int r = 0; r < 4; r++) {
                s[nt][r] = __builtin_amdgcn_exp2f(s[nt][r] - m_s);
                rs += s[nt][r];
            }
        rs += __shfl_xor(rs, 16);
        rs += __shfl_xor(rs, 32);
        l_s = l_s * al + rs;

        float alr[4];
#pragma unroll
        for (int r = 0; r < 4; r++) alr[r] = __shfl(al, quad * 4 + r, 16);
#pragma unroll
        for (int nt = 0; nt < 4; nt++)
#pragma unroll
            for (int r = 0; r < 4; r++) o[nt][r] *= alr[r];

#pragma unroll
        for (int nt = 0; nt < 4; nt++) {
            short4v pk;
#pragma unroll
            for (int r = 0; r < 4; r++) pk[r] = (short)f2bf(s[nt][r]);
            *(short4v*)&ppriv[lo * PSTR + nt * 16 + quad * 4] = pk;
        }
        short8 pf0 = *(const short8*)&ppriv[lo * PSTR + quad * 8];
        short8 pf1 = *(const short8*)&ppriv[lo * PSTR + 32 + quad * 8];

#pragma unroll
        for (int nt = 0; nt < 4; nt++) {
            const int row = nt * 16 + lo;
            short8 vf0 = *(const short8*)&vt_lds[row * 64 + ((quad ^ (row & 7)) * 8)];
            short8 vf1 = *(const short8*)&vt_lds[row * 64 + (((4 + quad) ^ (row & 7)) * 8)];
            o[nt] = __builtin_amdgcn_mfma_f32_16x16x32_bf16(pf0, vf0, o[nt], 0, 0, 0);
            o[nt] = __builtin_amdgcn_mfma_f32_16x16x32_bf16(pf1, vf1, o[nt], 0, 0, 0);
        }
        __syncthreads();
    }

    const int b = bh >> 4, h = bh & 15;
    float inv[4];
#pragma unroll
    for (int r = 0; r < 4; r++) inv[r] = 1.0f / __shfl(l_s, quad * 4 + r, 16);
#pragma unroll
    for (int nt = 0; nt < 4; nt++)
#pragma unroll
        for (int r = 0; r < 4; r++) {
            int srow = q0 + w * 16 + quad * 4 + r;
            attn_out[((size_t)b * SQL + srow) * HH + h * HDD + nt * 16 + lo] =
                f2bf(o[nt][r] * inv[r]);
        }
}

// ---------------- LayerNorm ----------------
__global__ __launch_bounds__(256) void ln_kernel(const float* __restrict__ x,
                                                 const float* __restrict__ g,
                                                 const float* __restrict__ bb,
                                                 float* __restrict__ out)
{
    const int row = blockIdx.x;
    const int t = threadIdx.x;
    const float* xr = x + (size_t)row * HH;
    float4 v = *(const float4*)(xr + t * 4);
    float s1 = v.x + v.y + v.z + v.w;
    float s2 = v.x * v.x + v.y * v.y + v.z * v.z + v.w * v.w;
#pragma unroll
    for (int off = 32; off; off >>= 1) { s1 += __shfl_xor(s1, off); s2 += __shfl_xor(s2, off); }
    __shared__ float red[8];
    if ((t & 63) == 0) { red[(t >> 6) * 2] = s1; red[(t >> 6) * 2 + 1] = s2; }
    __syncthreads();
    s1 = red[0] + red[2] + red[4] + red[6];
    s2 = red[1] + red[3] + red[5] + red[7];
    float mu = s1 * (1.0f / HH);
    float var = s2 * (1.0f / HH) - mu * mu;
    float rstd = rsqrtf(var + 1e-5f);
    float4 gg = *(const float4*)(g + t * 4);
    float4 b4 = *(const float4*)(bb + t * 4);
    float4 o;
    o.x = (v.x - mu) * rstd * gg.x + b4.x;
    o.y = (v.y - mu) * rstd * gg.y + b4.y;
    o.z = (v.z - mu) * rstd * gg.z + b4.z;
    o.w = (v.w - mu) * rstd * gg.w + b4.w;
    *(float4*)(out + (size_t)row * HH + t * 4) = o;
}

extern "C" void kernel_launch(void* const* d_in, const int* in_sizes, int n_in,
                              void* d_out, int out_size, void* d_ws, size_t ws_size,
                              hipStream_t stream)
{
    const float* query = (const float*)d_in[0];
    const float* key   = (const float*)d_in[1];
    const float* value = (const float*)d_in[2];
    // d_in[3] = causal_mask (tril by construction; causality hardcoded)
    const float* Wq = (const float*)d_in[4];
    const float* bq = (const float*)d_in[5];
    const float* Wk = (const float*)d_in[6];
    const float* bk = (const float*)d_in[7];
    const float* Wv = (const float*)d_in[8];
    const float* bv = (const float*)d_in[9];
    const float* Wo = (const float*)d_in[10];
    const float* bo = (const float*)d_in[11];
    const float* ln_g = (const float*)d_in[12];
    const float* ln_b = (const float*)d_in[13];
    float* out = (float*)d_out;

    char* wp = (char*)d_ws;
    auto alloc = [&](size_t bytes) { void* p = (void*)wp; wp += (bytes + 255) & ~(size_t)255; return p; };
    const int nW = HH * HH;    // 1M
    const int nX = MM * HH;    // 4M
    u16* wqb = (u16*)alloc((size_t)nW * 2);
    u16* wkb = (u16*)alloc((size_t)nW * 2);
    u16* wvb = (u16*)alloc((size_t)nW * 2);
    u16* wob = (u16*)alloc((size_t)nW * 2);
    u16* qbuf = (u16*)alloc((size_t)nX * 2);   // [b][h][s][d]
    u16* kbuf = (u16*)alloc((size_t)nX * 2);   // [b][h][s][d]
    u16* vbuf = (u16*)alloc((size_t)nX * 2);   // V^T [b][h][d][s]
    u16* attnb = (u16*)alloc((size_t)nX * 2);  // [b][s][h*d]
    float* projf = (float*)alloc((size_t)nX * 4);

    cvt_w_kernel<<<4096, 256, 0, stream>>>(Wq, Wk, Wv, Wo, wqb, wkb, wvb, wob);

    proj_kernel<<<dim3(32, 8, 3), 256, 0, stream>>>(
        query, key, value, wqb, wkb, wvb, bq, bk, bv, qbuf, kbuf, vbuf);

    attn_kernel<<<1024, 256, 0, stream>>>(qbuf, kbuf, vbuf, attnb);

    outproj_kernel<<<dim3(64, 8), 256, 0, stream>>>(attnb, wob, bo, query, projf);

    ln_kernel<<<MM, 256, 0, stream>>>(projf, ln_g, ln_b, out);
}

// Round 13
// 249.474 us; speedup vs baseline: 1.0344x; 1.0344x over previous
//
#include <hip/hip_runtime.h>
#include <hip/hip_bf16.h>

#define SQL 2048
#define SKL 2048
#define HH  1024
#define NHH 16
#define HDD 64
#define BB  2
#define MM  (BB*SQL)   // 4096 tokens

typedef __attribute__((ext_vector_type(8))) short short8;
typedef __attribute__((ext_vector_type(4))) short short4v;
typedef __attribute__((ext_vector_type(4))) float f32x4;
typedef unsigned short u16;

__device__ inline u16 f2bf(float f) {
    unsigned int u = __float_as_uint(f);
    u += 0x7fffu + ((u >> 16) & 1u);   // RNE
    return (u16)(u >> 16);
}

// pair-convert: compiler emits v_cvt_pk_bf16_f32 (intrinsic, NOT inline asm — m240)
__device__ inline unsigned int bf2_bits(float a, float b) {
    __hip_bfloat162 h = __float22bfloat162_rn(make_float2(a, b));
    unsigned int r;
    __builtin_memcpy(&r, &h, 4);
    return r;
}

__device__ inline void gl_lds16(const void* g, void* l) {
    __builtin_amdgcn_global_load_lds(
        (const __attribute__((address_space(1))) unsigned int*)g,
        (__attribute__((address_space(3))) unsigned int*)l, 16, 0, 0);
}

// ---------------- fused fp32 -> bf16 convert (all 7 tensors, 1 launch) ----------------
// R11's fuse-into-proj regressed +28 µs (serial reg-stage chain + fp32 re-reads);
// the standalone streaming pass is the measured-best form.
__global__ __launch_bounds__(256) void cvt_all_kernel(
    const float* __restrict__ q, const float* __restrict__ k, const float* __restrict__ v,
    const float* __restrict__ wq, const float* __restrict__ wk,
    const float* __restrict__ wv, const float* __restrict__ wo,
    u16* __restrict__ xq, u16* __restrict__ xk, u16* __restrict__ xv,
    u16* __restrict__ wqb, u16* __restrict__ wkb, u16* __restrict__ wvb, u16* __restrict__ wob)
{
    int b = blockIdx.x;
    const float* src; u16* dst;
    if      (b < 4096)  { src = q;  dst = xq; }
    else if (b < 8192)  { src = k;  dst = xk;  b -= 4096; }
    else if (b < 12288) { src = v;  dst = xv;  b -= 8192; }
    else if (b < 13312) { src = wq; dst = wqb; b -= 12288; }
    else if (b < 14336) { src = wk; dst = wkb; b -= 13312; }
    else if (b < 15360) { src = wv; dst = wvb; b -= 14336; }
    else                { src = wo; dst = wob; b -= 15360; }
    int i = (b * 256 + threadIdx.x) * 4;
    float4 vv = *(const float4*)(src + i);
    ushort4 oo;
    oo.x = f2bf(vv.x); oo.y = f2bf(vv.y); oo.z = f2bf(vv.z); oo.w = f2bf(vv.w);
    *(ushort4*)(dst + i) = oo;
}

// ---------------- fused q/k/v projection: C = A @ W^T (+bias) — R8 verbatim ----------------
// grid.z in {0:q, 1:k, 2:v}. 128x128 tile, BK=64 (R4: fewer drains = -9%).
// Coalesced epilogue via per-wave LDS transpose scratch (R8 WIN).
__global__ __launch_bounds__(256) void proj_kernel(
    const u16* __restrict__ xq, const u16* __restrict__ xk, const u16* __restrict__ xv,
    const u16* __restrict__ wqb, const u16* __restrict__ wkb, const u16* __restrict__ wvb,
    const float* __restrict__ bq, const float* __restrict__ bk, const float* __restrict__ bv,
    u16* __restrict__ oq, u16* __restrict__ ok, u16* __restrict__ ov)
{
    const int z = blockIdx.z;
    const u16* A      = (z == 0) ? xq  : (z == 1) ? xk  : xv;
    const u16* W      = (z == 0) ? wqb : (z == 1) ? wkb : wvb;
    const float* bias = (z == 0) ? bq  : (z == 1) ? bk  : bv;
    u16* outb         = (z == 0) ? oq  : (z == 1) ? ok  : ov;
    const float scale = (z == 0) ? 0.125f * 1.4426950408889634f : 1.0f;

    __shared__ u16 pool[2 * 128 * 64];   // K-loop: A tile | W tile; epilogue: 4x8KB wave scratch
    u16* lds_a = pool;
    u16* lds_b = pool + 128 * 64;

    const int t = threadIdx.x;
    const int lane = t & 63;
    const int quad = lane >> 4;
    const int lo = lane & 15;
    const int wv = t >> 6;
    const int wm = (wv >> 1) * 64, wn = (wv & 1) * 64;
    const int m0 = blockIdx.x * 128;
    const int n0 = blockIdx.y * 128;

    f32x4 acc[4][4];
#pragma unroll
    for (int i = 0; i < 4; i++)
#pragma unroll
        for (int j = 0; j < 4; j++) acc[i][j] = (f32x4){0.f, 0.f, 0.f, 0.f};

    int rr[4], cc[4];
#pragma unroll
    for (int u = 0; u < 4; u++) {
        int sl = u * 256 + t;
        rr[u] = sl >> 3;
        cc[u] = ((sl & 7) ^ (rr[u] & 7)) * 8;
    }

    for (int k0 = 0; k0 < HH; k0 += 64) {
#pragma unroll
        for (int u = 0; u < 4; u++) {
            gl_lds16(A + (size_t)(m0 + rr[u]) * HH + k0 + cc[u], &lds_a[(u * 256 + t) * 8]);
            gl_lds16(W + (size_t)(n0 + rr[u]) * HH + k0 + cc[u], &lds_b[(u * 256 + t) * 8]);
        }
        __syncthreads();
#pragma unroll
        for (int kk = 0; kk < 2; kk++) {
            short8 af[4], bf[4];
#pragma unroll
            for (int i = 0; i < 4; i++) {
                const int ra = wm + i * 16 + lo;
                const int rb = wn + i * 16 + lo;
                af[i] = *(const short8*)&lds_a[ra * 64 + (((kk * 4 + quad) ^ (ra & 7)) * 8)];
                bf[i] = *(const short8*)&lds_b[rb * 64 + (((kk * 4 + quad) ^ (rb & 7)) * 8)];
            }
            if (z == 2) {   // wave-uniform: C rows = tokens, cols = dims
#pragma unroll
                for (int i = 0; i < 4; i++)
#pragma unroll
                    for (int j = 0; j < 4; j++)
                        acc[i][j] = __builtin_amdgcn_mfma_f32_16x16x32_bf16(af[i], bf[j], acc[i][j], 0, 0, 0);
            } else {        // C rows = dims, cols = tokens
#pragma unroll
                for (int i = 0; i < 4; i++)
#pragma unroll
                    for (int j = 0; j < 4; j++)
                        acc[i][j] = __builtin_amdgcn_mfma_f32_16x16x32_bf16(bf[j], af[i], acc[i][j], 0, 0, 0);
            }
        }
        __syncthreads();
    }

    u16* cbuf = &pool[wv * 4096];   // per-wave 64x64 bf16 scratch, stride 64 u16

    if (z != 2) {
        // C^T: lane holds (d_local = wn-rel j*16+quad*4+r, tok_local = i*16+lo).
#pragma unroll
        for (int j = 0; j < 4; j++) {
            float4 b4 = *(const float4*)&bias[n0 + wn + j * 16 + quad * 4];
#pragma unroll
            for (int i = 0; i < 4; i++) {
                int tokl = i * 16 + lo;
                int lc = j * 2 + (quad >> 1);
                int phys = lc ^ (tokl & 7);
                uint2 pk;
                pk.x = bf2_bits((acc[i][j][0] + b4.x) * scale, (acc[i][j][1] + b4.y) * scale);
                pk.y = bf2_bits((acc[i][j][2] + b4.z) * scale, (acc[i][j][3] + b4.w) * scale);
                *(uint2*)&cbuf[tokl * 64 + phys * 8 + (quad & 1) * 4] = pk;
            }
        }
        __syncthreads();
#pragma unroll
        for (int it = 0; it < 8; it++) {
            int row = it * 8 + (lane >> 3);          // tok_local
            int lc2 = lane & 7;                      // d chunk
            short8 val = *(const short8*)&cbuf[row * 64 + ((lc2 ^ (row & 7)) * 8)];
            int tok = m0 + wm + row;
            int dgb = n0 + wn + lc2 * 8;
            int bi = tok >> 11, s = tok & 2047;
            int head = dgb >> 6, d = dgb & 63;
            *(short8*)&outb[(((size_t)bi * NHH + head) * SQL + s) * HDD + d] = val;
        }
    } else {
        // C: lane holds (tok_local = i*16+quad*4+r, d_local = j*16+lo).
#pragma unroll
        for (int j = 0; j < 4; j++) {
            float bsc = bias[n0 + wn + j * 16 + lo];
#pragma unroll
            for (int i = 0; i < 4; i++) {
                int dgl = j * 16 + lo;
                int lc = i * 2 + (quad >> 1);
                int phys = lc ^ (dgl & 7);
                uint2 pk;
                pk.x = bf2_bits(acc[i][j][0] + bsc, acc[i][j][1] + bsc);
                pk.y = bf2_bits(acc[i][j][2] + bsc, acc[i][j][3] + bsc);
                *(uint2*)&cbuf[dgl * 64 + phys * 8 + (quad & 1) * 4] = pk;
            }
        }
        __syncthreads();
#pragma unroll
        for (int it = 0; it < 8; it++) {
            int row = it * 8 + (lane >> 3);          // d_local
            int lc2 = lane & 7;                      // tok chunk
            short8 val = *(const short8*)&cbuf[row * 64 + ((lc2 ^ (row & 7)) * 8)];
            int dg = n0 + wn + row;
            int tokb = m0 + wm + lc2 * 8;
            int bi = tokb >> 11, s = tokb & 2047;
            int head = dg >> 6, d = dg & 63;
            *(short8*)&outb[(((size_t)bi * NHH + head) * HDD + d) * SKL + s] = val;
        }
    }
}

// ---------------- out-projection — R11 version (kept: inferred -14 µs) ----------------
// BM=64 tiles -> grid (64,8) = 512 blocks = 2/CU (R4 occupancy lever).
// Waves 2x2 of 32x64, acc[2][4]; swapped mfma + coalesced fp32 epilogue.
__global__ __launch_bounds__(256) void outproj_kernel(
    const u16* __restrict__ A, const u16* __restrict__ W,
    const float* __restrict__ bias, const float* __restrict__ resid,
    float* __restrict__ outf)
{
    __shared__ u16 pool[2 * 128 * 64];   // K-loop: A 8KB | W 16KB; epilogue: 4x8KB wave scratch
    u16* lds_a = pool;
    u16* lds_b = pool + 64 * 64;

    const int t = threadIdx.x;
    const int lane = t & 63;
    const int quad = lane >> 4;
    const int lo = lane & 15;
    const int wv = t >> 6;
    const int wm = (wv >> 1) * 32, wn = (wv & 1) * 64;
    const int m0 = blockIdx.x * 64;
    const int n0 = blockIdx.y * 128;

    f32x4 acc[2][4];
#pragma unroll
    for (int i = 0; i < 2; i++)
#pragma unroll
        for (int j = 0; j < 4; j++) acc[i][j] = (f32x4){0.f, 0.f, 0.f, 0.f};

    int rr[4], cc[4];
#pragma unroll
    for (int u = 0; u < 4; u++) {
        int sl = u * 256 + t;
        rr[u] = sl >> 3;
        cc[u] = ((sl & 7) ^ (rr[u] & 7)) * 8;
    }

    for (int k0 = 0; k0 < HH; k0 += 64) {
#pragma unroll
        for (int u = 0; u < 2; u++)   // A: 64 rows -> 2 slots/thread
            gl_lds16(A + (size_t)(m0 + rr[u]) * HH + k0 + cc[u], &lds_a[(u * 256 + t) * 8]);
#pragma unroll
        for (int u = 0; u < 4; u++)   // W: 128 rows -> 4 slots/thread
            gl_lds16(W + (size_t)(n0 + rr[u]) * HH + k0 + cc[u], &lds_b[(u * 256 + t) * 8]);
        __syncthreads();
#pragma unroll
        for (int kk = 0; kk < 2; kk++) {
            short8 af[2], bf[4];
#pragma unroll
            for (int i = 0; i < 2; i++) {
                const int ra = wm + i * 16 + lo;
                af[i] = *(const short8*)&lds_a[ra * 64 + (((kk * 4 + quad) ^ (ra & 7)) * 8)];
            }
#pragma unroll
            for (int j = 0; j < 4; j++) {
                const int rb = wn + j * 16 + lo;
                bf[j] = *(const short8*)&lds_b[rb * 64 + (((kk * 4 + quad) ^ (rb & 7)) * 8)];
            }
#pragma unroll
            for (int i = 0; i < 2; i++)
#pragma unroll
                for (int j = 0; j < 4; j++)
                    acc[i][j] = __builtin_amdgcn_mfma_f32_16x16x32_bf16(bf[j], af[i], acc[i][j], 0, 0, 0);
        }
        __syncthreads();
    }

    // epilogue: lane holds (col_local = j*16+quad*4+r, tok_local = i*16+lo).
    float* cbuf = (float*)&pool[wv * 4096];   // 8KB per wave
#pragma unroll
    for (int j = 0; j < 4; j++) {
        float4 b4 = *(const float4*)&bias[n0 + wn + j * 16 + quad * 4];
#pragma unroll
        for (int i = 0; i < 2; i++) {
            int tl = i * 16 + lo;                // 0..31
            int lc = j * 4 + quad;               // 16B chunk (4 f32), 0..15
            int phys = lc ^ (tl & 7);
            f32x4 vq;
            vq[0] = acc[i][j][0] + b4.x; vq[1] = acc[i][j][1] + b4.y;
            vq[2] = acc[i][j][2] + b4.z; vq[3] = acc[i][j][3] + b4.w;
            *(f32x4*)&cbuf[tl * 64 + phys * 4] = vq;
        }
    }
    // wave-private scratch: same-wave ds_write -> ds_read ordered via lgkmcnt
#pragma unroll
    for (int it = 0; it < 8; it++) {
        int rowl = it * 4 + (lane >> 4);         // 0..31
        int lc2 = lane & 15;
        f32x4 val = *(const f32x4*)&cbuf[rowl * 64 + ((lc2 ^ (rowl & 7)) * 4)];
        int tok = m0 + wm + rowl;
        int col = n0 + wn + lc2 * 4;
        const float4 rd = *(const float4*)&resid[(size_t)tok * HH + col];
        float4 o;
        o.x = val[0] + rd.x; o.y = val[1] + rd.y;
        o.z = val[2] + rd.z; o.w = val[3] + rd.w;
        *(float4*)&outf[(size_t)tok * HH + col] = o;
    }
}

// ---------------- Flash attention (S^T orientation) — R8 verbatim (best: 49.4 µs) --------
// R9 (cvt_pk/defer-max/setprio) and R10 (LDS-staged O epilogue) both A/B-regressed:
// the per-tile chain is latency-bound; removed VALU was idle-cycle filler.
#define PSTR 72   // [16 q][64 key] P tile row stride (u16): 144 B = 16B-aligned, bank-spread

__global__ __launch_bounds__(256) void attn_kernel(
    const u16* __restrict__ qb, const u16* __restrict__ kb, const u16* __restrict__ vtb,
    u16* __restrict__ attn_out)
{
    __shared__ u16 k_lds[64 * 64];
    __shared__ u16 vt_lds[64 * 64];
    __shared__ u16 p_lds[4 * 16 * PSTR];

    const int t = threadIdx.x;
    const int lane = t & 63;
    const int quad = lane >> 4;
    const int lo = lane & 15;
    const int w = t >> 6;
    const int qt = (SQL / 64 - 1) - (blockIdx.x >> 5);  // heavy q-tiles first
    const int bh = blockIdx.x & 31;
    const int q0 = qt * 64;

    const u16* qbase = qb + ((size_t)bh * SQL + q0 + w * 16 + lo) * HDD + quad * 8;
    short8 qf0 = *(const short8*)qbase;
    short8 qf1 = *(const short8*)(qbase + 32);

    float m_s = -__builtin_inff(), l_s = 0.f;
    f32x4 o[4];
#pragma unroll
    for (int j = 0; j < 4; j++) o[j] = (f32x4){0.f, 0.f, 0.f, 0.f};

    const int sl0 = t, sl1 = 256 + t;
    const int r0 = sl0 >> 3, c0 = ((sl0 & 7) ^ (r0 & 7)) * 8;
    const int r1 = sl1 >> 3, c1 = ((sl1 & 7) ^ (r1 & 7)) * 8;
    const u16* kbh = kb + (size_t)bh * SKL * HDD;
    const u16* vbh = vtb + (size_t)bh * HDD * SKL;
    u16* ppriv = &p_lds[w * 16 * PSTR];

    for (int kt = 0; kt <= qt; kt++) {
        const int k0 = kt * 64;
        gl_lds16(kbh + (size_t)(k0 + r0) * HDD + c0, &k_lds[sl0 * 8]);
        gl_lds16(kbh + (size_t)(k0 + r1) * HDD + c1, &k_lds[sl1 * 8]);
        gl_lds16(vbh + (size_t)r0 * SKL + k0 + c0, &vt_lds[sl0 * 8]);
        gl_lds16(vbh + (size_t)r1 * SKL + k0 + c1, &vt_lds[sl1 * 8]);
        __syncthreads();

        f32x4 s[4];
#pragma unroll
        for (int nt = 0; nt < 4; nt++) {
            const int row = nt * 16 + lo;
            short8 kf0 = *(const short8*)&k_lds[row * 64 + ((quad ^ (row & 7)) * 8)];
            short8 kf1 = *(const short8*)&k_lds[row * 64 + (((4 + quad) ^ (row & 7)) * 8)];
            s[nt] = (f32x4){0.f, 0.f, 0.f, 0.f};
            s[nt] = __builtin_amdgcn_mfma_f32_16x16x32_bf16(kf0, qf0, s[nt], 0, 0, 0);
            s[nt] = __builtin_amdgcn_mfma_f32_16x16x32_bf16(kf1, qf1, s[nt], 0, 0, 0);
        }
        if (kt == qt) {
            const int ql = w * 16 + lo;
#pragma unroll
            for (int nt = 0; nt < 4; nt++)
#pragma unroll
                for (int r = 0; r < 4; r++)
                    if (nt * 16 + quad * 4 + r > ql) s[nt][r] = -__builtin_inff();
        }

        float mx = s[0][0];
#pragma unroll
        for (int nt = 0; nt < 4; nt++)
#pragma unroll
            for (int r = 0; r < 4; r++) mx = fmaxf(mx, s[nt][r]);
        mx = fmaxf(mx, __shfl_xor(mx, 16));
        mx = fmaxf(mx, __shfl_xor(mx, 32));
        float mnew = fmaxf(m_s, mx);
        float al = __builtin_amdgcn_exp2f(m_s - mnew);
        m_s = mnew;
        float rs = 0.f;
#pragma unroll
        for (int nt = 0; nt < 4; nt++)
#pragma unroll
            for (int r = 0; r < 4; r++) {
                s[nt][r] = __builtin_amdgcn_exp2f(s[nt][r] - m_s);
                rs += s[nt][r];
            }
        rs += __shfl_xor(rs, 16);
        rs += __shfl_xor(rs, 32);
        l_s = l_s * al + rs;

        float alr[4];
#pragma unroll
        for (int r = 0; r < 4; r++) alr[r] = __shfl(al, quad * 4 + r, 16);
#pragma unroll
        for (int nt = 0; nt < 4; nt++)
#pragma unroll
            for (int r = 0; r < 4; r++) o[nt][r] *= alr[r];

#pragma unroll
        for (int nt = 0; nt < 4; nt++) {
            short4v pk;
#pragma unroll
            for (int r = 0; r < 4; r++) pk[r] = (short)f2bf(s[nt][r]);
            *(short4v*)&ppriv[lo * PSTR + nt * 16 + quad * 4] = pk;
        }
        short8 pf0 = *(const short8*)&ppriv[lo * PSTR + quad * 8];
        short8 pf1 = *(const short8*)&ppriv[lo * PSTR + 32 + quad * 8];

#pragma unroll
        for (int nt = 0; nt < 4; nt++) {
            const int row = nt * 16 + lo;
            short8 vf0 = *(const short8*)&vt_lds[row * 64 + ((quad ^ (row & 7)) * 8)];
            short8 vf1 = *(const short8*)&vt_lds[row * 64 + (((4 + quad) ^ (row & 7)) * 8)];
            o[nt] = __builtin_amdgcn_mfma_f32_16x16x32_bf16(pf0, vf0, o[nt], 0, 0, 0);
            o[nt] = __builtin_amdgcn_mfma_f32_16x16x32_bf16(pf1, vf1, o[nt], 0, 0, 0);
        }
        __syncthreads();
    }

    const int b = bh >> 4, h = bh & 15;
    float inv[4];
#pragma unroll
    for (int r = 0; r < 4; r++) inv[r] = 1.0f / __shfl(l_s, quad * 4 + r, 16);
#pragma unroll
    for (int nt = 0; nt < 4; nt++)
#pragma unroll
        for (int r = 0; r < 4; r++) {
            int srow = q0 + w * 16 + quad * 4 + r;
            attn_out[((size_t)b * SQL + srow) * HH + h * HDD + nt * 16 + lo] =
                f2bf(o[nt][r] * inv[r]);
        }
}

// ---------------- LayerNorm ----------------
__global__ __launch_bounds__(256) void ln_kernel(const float* __restrict__ x,
                                                 const float* __restrict__ g,
                                                 const float* __restrict__ bb,
                                                 float* __restrict__ out)
{
    const int row = blockIdx.x;
    const int t = threadIdx.x;
    const float* xr = x + (size_t)row * HH;
    float4 v = *(const float4*)(xr + t * 4);
    float s1 = v.x + v.y + v.z + v.w;
    float s2 = v.x * v.x + v.y * v.y + v.z * v.z + v.w * v.w;
#pragma unroll
    for (int off = 32; off; off >>= 1) { s1 += __shfl_xor(s1, off); s2 += __shfl_xor(s2, off); }
    __shared__ float red[8];
    if ((t & 63) == 0) { red[(t >> 6) * 2] = s1; red[(t >> 6) * 2 + 1] = s2; }
    __syncthreads();
    s1 = red[0] + red[2] + red[4] + red[6];
    s2 = red[1] + red[3] + red[5] + red[7];
    float mu = s1 * (1.0f / HH);
    float var = s2 * (1.0f / HH) - mu * mu;
    float rstd = rsqrtf(var + 1e-5f);
    float4 gg = *(const float4*)(g + t * 4);
    float4 b4 = *(const float4*)(bb + t * 4);
    float4 o;
    o.x = (v.x - mu) * rstd * gg.x + b4.x;
    o.y = (v.y - mu) * rstd * gg.y + b4.y;
    o.z = (v.z - mu) * rstd * gg.z + b4.z;
    o.w = (v.w - mu) * rstd * gg.w + b4.w;
    *(float4*)(out + (size_t)row * HH + t * 4) = o;
}

extern "C" void kernel_launch(void* const* d_in, const int* in_sizes, int n_in,
                              void* d_out, int out_size, void* d_ws, size_t ws_size,
                              hipStream_t stream)
{
    const float* query = (const float*)d_in[0];
    const float* key   = (const float*)d_in[1];
    const float* value = (const float*)d_in[2];
    // d_in[3] = causal_mask (tril by construction; causality hardcoded)
    const float* Wq = (const float*)d_in[4];
    const float* bq = (const float*)d_in[5];
    const float* Wk = (const float*)d_in[6];
    const float* bk = (const float*)d_in[7];
    const float* Wv = (const float*)d_in[8];
    const float* bv = (const float*)d_in[9];
    const float* Wo = (const float*)d_in[10];
    const float* bo = (const float*)d_in[11];
    const float* ln_g = (const float*)d_in[12];
    const float* ln_b = (const float*)d_in[13];
    float* out = (float*)d_out;

    char* wp = (char*)d_ws;
    auto alloc = [&](size_t bytes) { void* p = (void*)wp; wp += (bytes + 255) & ~(size_t)255; return p; };
    const int nW = HH * HH;    // 1M
    const int nX = MM * HH;    // 4M
    u16* wqb = (u16*)alloc((size_t)nW * 2);
    u16* wkb = (u16*)alloc((size_t)nW * 2);
    u16* wvb = (u16*)alloc((size_t)nW * 2);
    u16* wob = (u16*)alloc((size_t)nW * 2);
    u16* xq  = (u16*)alloc((size_t)nX * 2);
    u16* xk  = (u16*)alloc((size_t)nX * 2);
    u16* xv  = (u16*)alloc((size_t)nX * 2);
    u16* qbuf = (u16*)alloc((size_t)nX * 2);   // [b][h][s][d]
    u16* kbuf = (u16*)alloc((size_t)nX * 2);   // [b][h][s][d]
    u16* vbuf = (u16*)alloc((size_t)nX * 2);   // V^T [b][h][d][s]
    u16* attnb = (u16*)alloc((size_t)nX * 2);  // [b][s][h*d]
    float* projf = (float*)alloc((size_t)nX * 4);

    cvt_all_kernel<<<16384, 256, 0, stream>>>(query, key, value, Wq, Wk, Wv, Wo,
                                              xq, xk, xv, wqb, wkb, wvb, wob);

    proj_kernel<<<dim3(32, 8, 3), 256, 0, stream>>>(
        xq, xk, xv, wqb, wkb, wvb, bq, bk, bv, qbuf, kbuf, vbuf);

    attn_kernel<<<1024, 256, 0, stream>>>(qbuf, kbuf, vbuf, attnb);

    outproj_kernel<<<dim3(64, 8), 256, 0, stream>>>(attnb, wob, bo, query, projf);

    ln_kernel<<<MM, 256, 0, stream>>>(projf, ln_g, ln_b, out);
}

// Round 14
// 246.140 us; speedup vs baseline: 1.0484x; 1.0135x over previous
//
#include <hip/hip_runtime.h>
#include <hip/hip_bf16.h>

#define SQL 2048
#define SKL 2048
#define HH  1024
#define NHH 16
#define HDD 64
#define BB  2
#define MM  (BB*SQL)   // 4096 tokens

typedef __attribute__((ext_vector_type(8))) short short8;
typedef __attribute__((ext_vector_type(4))) short short4v;
typedef __attribute__((ext_vector_type(4))) float f32x4;
typedef unsigned short u16;

__device__ inline u16 f2bf(float f) {
    unsigned int u = __float_as_uint(f);
    u += 0x7fffu + ((u >> 16) & 1u);   // RNE
    return (u16)(u >> 16);
}

// pair-convert: compiler emits v_cvt_pk_bf16_f32 (intrinsic, NOT inline asm — m240)
__device__ inline unsigned int bf2_bits(float a, float b) {
    __hip_bfloat162 h = __float22bfloat162_rn(make_float2(a, b));
    unsigned int r;
    __builtin_memcpy(&r, &h, 4);
    return r;
}

__device__ inline void gl_lds16(const void* g, void* l) {
    __builtin_amdgcn_global_load_lds(
        (const __attribute__((address_space(1))) unsigned int*)g,
        (__attribute__((address_space(3))) unsigned int*)l, 16, 0, 0);
}

// counted-vmcnt pipeline primitives (T4, m218): memory-clobbered so the
// scheduler cannot move VMEM/DS ops across them.
__device__ inline void wait_vmcnt4() { asm volatile("s_waitcnt vmcnt(4)" ::: "memory"); }
__device__ inline void wait_vmcnt0() { asm volatile("s_waitcnt vmcnt(0)" ::: "memory"); }
__device__ inline void wait_lgkm0()  { asm volatile("s_waitcnt lgkmcnt(0)" ::: "memory"); }
__device__ inline void fence()       { asm volatile("" ::: "memory"); }

// ---------------- fused fp32 -> bf16 convert (all 7 tensors, 1 launch) ----------------
__global__ __launch_bounds__(256) void cvt_all_kernel(
    const float* __restrict__ q, const float* __restrict__ k, const float* __restrict__ v,
    const float* __restrict__ wq, const float* __restrict__ wk,
    const float* __restrict__ wv, const float* __restrict__ wo,
    u16* __restrict__ xq, u16* __restrict__ xk, u16* __restrict__ xv,
    u16* __restrict__ wqb, u16* __restrict__ wkb, u16* __restrict__ wvb, u16* __restrict__ wob)
{
    int b = blockIdx.x;
    const float* src; u16* dst;
    if      (b < 4096)  { src = q;  dst = xq; }
    else if (b < 8192)  { src = k;  dst = xk;  b -= 4096; }
    else if (b < 12288) { src = v;  dst = xv;  b -= 8192; }
    else if (b < 13312) { src = wq; dst = wqb; b -= 12288; }
    else if (b < 14336) { src = wk; dst = wkb; b -= 13312; }
    else if (b < 15360) { src = wv; dst = wvb; b -= 14336; }
    else                { src = wo; dst = wob; b -= 15360; }
    int i = (b * 256 + threadIdx.x) * 4;
    float4 vv = *(const float4*)(src + i);
    ushort4 oo;
    oo.x = f2bf(vv.x); oo.y = f2bf(vv.y); oo.z = f2bf(vv.z); oo.w = f2bf(vv.w);
    *(ushort4*)(dst + i) = oo;
}

// ---------------- fused q/k/v projection: C = A @ W^T (+bias) ----------------
// R14: counted-vmcnt double-buffer (T3 minimum + T4). BK=32 x 2 buffers
// (4 x 8KB = 32 KB, occupancy unchanged). Per phase: stage(next) ->
// vmcnt(4) [next's 4 loads STAY IN FLIGHT] -> raw s_barrier -> ds_read+MFMA
// -> lgkmcnt(0) -> raw s_barrier. Never vmcnt(0) in steady state — this is
// what R3's __syncthreads dbuf (full drain, -15%) was missing.
// R8-WIN epilogue: coalesced stores via per-wave LDS transpose scratch.
__global__ __launch_bounds__(256) void proj_kernel(
    const u16* __restrict__ xq, const u16* __restrict__ xk, const u16* __restrict__ xv,
    const u16* __restrict__ wqb, const u16* __restrict__ wkb, const u16* __restrict__ wvb,
    const float* __restrict__ bq, const float* __restrict__ bk, const float* __restrict__ bv,
    u16* __restrict__ oq, u16* __restrict__ ok, u16* __restrict__ ov)
{
    const int z = blockIdx.z;
    const u16* A      = (z == 0) ? xq  : (z == 1) ? xk  : xv;
    const u16* W      = (z == 0) ? wqb : (z == 1) ? wkb : wvb;
    const float* bias = (z == 0) ? bq  : (z == 1) ? bk  : bv;
    u16* outb         = (z == 0) ? oq  : (z == 1) ? ok  : ov;
    const float scale = (z == 0) ? 0.125f * 1.4426950408889634f : 1.0f;

    __shared__ u16 pool[2 * 128 * 64];   // [A0|A1|W0|W1] 8KB each; epilogue: 4x8KB wave scratch
    u16* A0 = pool;
    u16* A1 = pool + 4096;
    u16* W0 = pool + 8192;
    u16* W1 = pool + 12288;

    const int t = threadIdx.x;
    const int lane = t & 63;
    const int quad = lane >> 4;
    const int lo = lane & 15;
    const int wv = t >> 6;
    const int wm = (wv >> 1) * 64, wn = (wv & 1) * 64;
    const int m0 = blockIdx.x * 128;
    const int n0 = blockIdx.y * 128;

    f32x4 acc[4][4];
#pragma unroll
    for (int i = 0; i < 4; i++)
#pragma unroll
        for (int j = 0; j < 4; j++) acc[i][j] = (f32x4){0.f, 0.f, 0.f, 0.f};

    // BK=32 staging: slot s covers row s>>2, chunk-slot s&3; global chunk (s&3)^((r>>1)&3)
    const int sl0 = t, sl1 = 256 + t;
    const int r0s = sl0 >> 2, c0s = ((sl0 & 3) ^ ((r0s >> 1) & 3)) * 8;
    const int r1s = sl1 >> 2, c1s = ((sl1 & 3) ^ ((r1s >> 1) & 3)) * 8;

    auto stage = [&](u16* la, u16* lb, int kt) {
        gl_lds16(A + (size_t)(m0 + r0s) * HH + kt + c0s, &la[sl0 * 8]);
        gl_lds16(A + (size_t)(m0 + r1s) * HH + kt + c1s, &la[sl1 * 8]);
        gl_lds16(W + (size_t)(n0 + r0s) * HH + kt + c0s, &lb[sl0 * 8]);
        gl_lds16(W + (size_t)(n0 + r1s) * HH + kt + c1s, &lb[sl1 * 8]);
    };
    auto compute = [&](const u16* la, const u16* lb) {
        short8 af[4], bf[4];
#pragma unroll
        for (int i = 0; i < 4; i++) {
            const int ra = wm + i * 16 + lo;
            const int rb = wn + i * 16 + lo;
            af[i] = *(const short8*)&la[ra * 32 + ((quad ^ ((ra >> 1) & 3)) * 8)];
            bf[i] = *(const short8*)&lb[rb * 32 + ((quad ^ ((rb >> 1) & 3)) * 8)];
        }
        if (z == 2) {   // wave-uniform: C rows = tokens, cols = dims
#pragma unroll
            for (int i = 0; i < 4; i++)
#pragma unroll
                for (int j = 0; j < 4; j++)
                    acc[i][j] = __builtin_amdgcn_mfma_f32_16x16x32_bf16(af[i], bf[j], acc[i][j], 0, 0, 0);
        } else {        // C rows = dims, cols = tokens
#pragma unroll
            for (int i = 0; i < 4; i++)
#pragma unroll
                for (int j = 0; j < 4; j++)
                    acc[i][j] = __builtin_amdgcn_mfma_f32_16x16x32_bf16(bf[j], af[i], acc[i][j], 0, 0, 0);
        }
    };

    stage(A0, W0, 0);                       // prologue: tile 0 in flight
    for (int k0 = 0; k0 < HH; k0 += 64) {
        // phase 0: compute buf0 (tile k0); prefetch tile k0+32 into buf1
        stage(A1, W1, k0 + 32);             // k0+32 <= 992 < HH always
        wait_vmcnt4();                      // buf0's 4 oldest landed; buf1's stay in flight
        __builtin_amdgcn_s_barrier();       // all waves' buf0 loads landed
        fence();                            // ds_reads stay below the barrier
        compute(A0, W0);
        wait_lgkm0();                       // reads in regs before buf0 is re-staged
        __builtin_amdgcn_s_barrier();
        fence();
        // phase 1: compute buf1 (tile k0+32); prefetch tile k0+64 into buf0
        if (k0 + 64 < HH) { stage(A0, W0, k0 + 64); wait_vmcnt4(); }
        else              { wait_vmcnt0(); }
        __builtin_amdgcn_s_barrier();
        fence();
        compute(A1, W1);
        wait_lgkm0();
        __builtin_amdgcn_s_barrier();
        fence();
    }

    u16* cbuf = &pool[wv * 4096];   // per-wave 64x64 bf16 scratch, stride 64 u16

    if (z != 2) {
        // C^T: lane holds (d_local = wn-rel j*16+quad*4+r, tok_local = i*16+lo).
#pragma unroll
        for (int j = 0; j < 4; j++) {
            float4 b4 = *(const float4*)&bias[n0 + wn + j * 16 + quad * 4];
#pragma unroll
            for (int i = 0; i < 4; i++) {
                int tokl = i * 16 + lo;
                int lc = j * 2 + (quad >> 1);
                int phys = lc ^ (tokl & 7);
                uint2 pk;
                pk.x = bf2_bits((acc[i][j][0] + b4.x) * scale, (acc[i][j][1] + b4.y) * scale);
                pk.y = bf2_bits((acc[i][j][2] + b4.z) * scale, (acc[i][j][3] + b4.w) * scale);
                *(uint2*)&cbuf[tokl * 64 + phys * 8 + (quad & 1) * 4] = pk;
            }
        }
        __syncthreads();
#pragma unroll
        for (int it = 0; it < 8; it++) {
            int row = it * 8 + (lane >> 3);          // tok_local
            int lc2 = lane & 7;                      // d chunk
            short8 val = *(const short8*)&cbuf[row * 64 + ((lc2 ^ (row & 7)) * 8)];
            int tok = m0 + wm + row;
            int dgb = n0 + wn + lc2 * 8;
            int bi = tok >> 11, s = tok & 2047;
            int head = dgb >> 6, d = dgb & 63;
            *(short8*)&outb[(((size_t)bi * NHH + head) * SQL + s) * HDD + d] = val;
        }
    } else {
        // C: lane holds (tok_local = i*16+quad*4+r, d_local = j*16+lo).
#pragma unroll
        for (int j = 0; j < 4; j++) {
            float bsc = bias[n0 + wn + j * 16 + lo];
#pragma unroll
            for (int i = 0; i < 4; i++) {
                int dgl = j * 16 + lo;
                int lc = i * 2 + (quad >> 1);
                int phys = lc ^ (dgl & 7);
                uint2 pk;
                pk.x = bf2_bits(acc[i][j][0] + bsc, acc[i][j][1] + bsc);
                pk.y = bf2_bits(acc[i][j][2] + bsc, acc[i][j][3] + bsc);
                *(uint2*)&cbuf[dgl * 64 + phys * 8 + (quad & 1) * 4] = pk;
            }
        }
        __syncthreads();
#pragma unroll
        for (int it = 0; it < 8; it++) {
            int row = it * 8 + (lane >> 3);          // d_local
            int lc2 = lane & 7;                      // tok chunk
            short8 val = *(const short8*)&cbuf[row * 64 + ((lc2 ^ (row & 7)) * 8)];
            int dg = n0 + wn + row;
            int tokb = m0 + wm + lc2 * 8;
            int bi = tokb >> 11, s = tokb & 2047;
            int head = dg >> 6, d = dg & 63;
            *(short8*)&outb[(((size_t)bi * NHH + head) * HDD + d) * SKL + s] = val;
        }
    }
}

// ---------------- out-projection — R13 version verbatim (validated -4.5 µs) ----------------
// BM=64 tiles -> grid (64,8) = 512 blocks = 2/CU (R4 occupancy lever).
// Waves 2x2 of 32x64, acc[2][4]; swapped mfma + coalesced fp32 epilogue.
__global__ __launch_bounds__(256) void outproj_kernel(
    const u16* __restrict__ A, const u16* __restrict__ W,
    const float* __restrict__ bias, const float* __restrict__ resid,
    float* __restrict__ outf)
{
    __shared__ u16 pool[2 * 128 * 64];   // K-loop: A 8KB | W 16KB; epilogue: 4x8KB wave scratch
    u16* lds_a = pool;
    u16* lds_b = pool + 64 * 64;

    const int t = threadIdx.x;
    const int lane = t & 63;
    const int quad = lane >> 4;
    const int lo = lane & 15;
    const int wv = t >> 6;
    const int wm = (wv >> 1) * 32, wn = (wv & 1) * 64;
    const int m0 = blockIdx.x * 64;
    const int n0 = blockIdx.y * 128;

    f32x4 acc[2][4];
#pragma unroll
    for (int i = 0; i < 2; i++)
#pragma unroll
        for (int j = 0; j < 4; j++) acc[i][j] = (f32x4){0.f, 0.f, 0.f, 0.f};

    int rr[4], cc[4];
#pragma unroll
    for (int u = 0; u < 4; u++) {
        int sl = u * 256 + t;
        rr[u] = sl >> 3;
        cc[u] = ((sl & 7) ^ (rr[u] & 7)) * 8;
    }

    for (int k0 = 0; k0 < HH; k0 += 64) {
#pragma unroll
        for (int u = 0; u < 2; u++)   // A: 64 rows -> 2 slots/thread
            gl_lds16(A + (size_t)(m0 + rr[u]) * HH + k0 + cc[u], &lds_a[(u * 256 + t) * 8]);
#pragma unroll
        for (int u = 0; u < 4; u++)   // W: 128 rows -> 4 slots/thread
            gl_lds16(W + (size_t)(n0 + rr[u]) * HH + k0 + cc[u], &lds_b[(u * 256 + t) * 8]);
        __syncthreads();
#pragma unroll
        for (int kk = 0; kk < 2; kk++) {
            short8 af[2], bf[4];
#pragma unroll
            for (int i = 0; i < 2; i++) {
                const int ra = wm + i * 16 + lo;
                af[i] = *(const short8*)&lds_a[ra * 64 + (((kk * 4 + quad) ^ (ra & 7)) * 8)];
            }
#pragma unroll
            for (int j = 0; j < 4; j++) {
                const int rb = wn + j * 16 + lo;
                bf[j] = *(const short8*)&lds_b[rb * 64 + (((kk * 4 + quad) ^ (rb & 7)) * 8)];
            }
#pragma unroll
            for (int i = 0; i < 2; i++)
#pragma unroll
                for (int j = 0; j < 4; j++)
                    acc[i][j] = __builtin_amdgcn_mfma_f32_16x16x32_bf16(bf[j], af[i], acc[i][j], 0, 0, 0);
        }
        __syncthreads();
    }

    // epilogue: lane holds (col_local = j*16+quad*4+r, tok_local = i*16+lo).
    float* cbuf = (float*)&pool[wv * 4096];   // 8KB per wave
#pragma unroll
    for (int j = 0; j < 4; j++) {
        float4 b4 = *(const float4*)&bias[n0 + wn + j * 16 + quad * 4];
#pragma unroll
        for (int i = 0; i < 2; i++) {
            int tl = i * 16 + lo;                // 0..31
            int lc = j * 4 + quad;               // 16B chunk (4 f32), 0..15
            int phys = lc ^ (tl & 7);
            f32x4 vq;
            vq[0] = acc[i][j][0] + b4.x; vq[1] = acc[i][j][1] + b4.y;
            vq[2] = acc[i][j][2] + b4.z; vq[3] = acc[i][j][3] + b4.w;
            *(f32x4*)&cbuf[tl * 64 + phys * 4] = vq;
        }
    }
    // wave-private scratch: same-wave ds_write -> ds_read ordered via lgkmcnt
#pragma unroll
    for (int it = 0; it < 8; it++) {
        int rowl = it * 4 + (lane >> 4);         // 0..31
        int lc2 = lane & 15;
        f32x4 val = *(const f32x4*)&cbuf[rowl * 64 + ((lc2 ^ (rowl & 7)) * 4)];
        int tok = m0 + wm + rowl;
        int col = n0 + wn + lc2 * 4;
        const float4 rd = *(const float4*)&resid[(size_t)tok * HH + col];
        float4 o;
        o.x = val[0] + rd.x; o.y = val[1] + rd.y;
        o.z = val[2] + rd.z; o.w = val[3] + rd.w;
        *(float4*)&outf[(size_t)tok * HH + col] = o;
    }
}

// ---------------- Flash attention (S^T orientation) — R8 verbatim (best: ~50 µs) --------
// R9 (cvt_pk/defer-max/setprio) and R10 (LDS-staged O epilogue) both A/B-regressed:
// the per-tile chain is latency-bound; removed VALU was idle-cycle filler.
#define PSTR 72   // [16 q][64 key] P tile row stride (u16): 144 B = 16B-aligned, bank-spread

__global__ __launch_bounds__(256) void attn_kernel(
    const u16* __restrict__ qb, const u16* __restrict__ kb, const u16* __restrict__ vtb,
    u16* __restrict__ attn_out)
{
    __shared__ u16 k_lds[64 * 64];
    __shared__ u16 vt_lds[64 * 64];
    __shared__ u16 p_lds[4 * 16 * PSTR];

    const int t = threadIdx.x;
    const int lane = t & 63;
    const int quad = lane >> 4;
    const int lo = lane & 15;
    const int w = t >> 6;
    const int qt = (SQL / 64 - 1) - (blockIdx.x >> 5);  // heavy q-tiles first
    const int bh = blockIdx.x & 31;
    const int q0 = qt * 64;

    const u16* qbase = qb + ((size_t)bh * SQL + q0 + w * 16 + lo) * HDD + quad * 8;
    short8 qf0 = *(const short8*)qbase;
    short8 qf1 = *(const short8*)(qbase + 32);

    float m_s = -__builtin_inff(), l_s = 0.f;
    f32x4 o[4];
#pragma unroll
    for (int j = 0; j < 4; j++) o[j] = (f32x4){0.f, 0.f, 0.f, 0.f};

    const int sl0 = t, sl1 = 256 + t;
    const int r0 = sl0 >> 3, c0 = ((sl0 & 7) ^ (r0 & 7)) * 8;
    const int r1 = sl1 >> 3, c1 = ((sl1 & 7) ^ (r1 & 7)) * 8;
    const u16* kbh = kb + (size_t)bh * SKL * HDD;
    const u16* vbh = vtb + (size_t)bh * HDD * SKL;
    u16* ppriv = &p_lds[w * 16 * PSTR];

    for (int kt = 0; kt <= qt; kt++) {
        const int k0 = kt * 64;
        gl_lds16(kbh + (size_t)(k0 + r0) * HDD + c0, &k_lds[sl0 * 8]);
        gl_lds16(kbh + (size_t)(k0 + r1) * HDD + c1, &k_lds[sl1 * 8]);
        gl_lds16(vbh + (size_t)r0 * SKL + k0 + c0, &vt_lds[sl0 * 8]);
        gl_lds16(vbh + (size_t)r1 * SKL + k0 + c1, &vt_lds[sl1 * 8]);
        __syncthreads();

        f32x4 s[4];
#pragma unroll
        for (int nt = 0; nt < 4; nt++) {
            const int row = nt * 16 + lo;
            short8 kf0 = *(const short8*)&k_lds[row * 64 + ((quad ^ (row & 7)) * 8)];
            short8 kf1 = *(const short8*)&k_lds[row * 64 + (((4 + quad) ^ (row & 7)) * 8)];
            s[nt] = (f32x4){0.f, 0.f, 0.f, 0.f};
            s[nt] = __builtin_amdgcn_mfma_f32_16x16x32_bf16(kf0, qf0, s[nt], 0, 0, 0);
            s[nt] = __builtin_amdgcn_mfma_f32_16x16x32_bf16(kf1, qf1, s[nt], 0, 0, 0);
        }
        if (kt == qt) {
            const int ql = w * 16 + lo;
#pragma unroll
            for (int nt = 0; nt < 4; nt++)
#pragma unroll
                for (int r = 0; r < 4; r++)
                    if (nt * 16 + quad * 4 + r > ql) s[nt][r] = -__builtin_inff();
        }

        float mx = s[0][0];
#pragma unroll
        for (int nt = 0; nt < 4; nt++)
#pragma unroll
            for (int r = 0; r < 4; r++) mx = fmaxf(mx, s[nt][r]);
        mx = fmaxf(mx, __shfl_xor(mx, 16));
        mx = fmaxf(mx, __shfl_xor(mx, 32));
        float mnew = fmaxf(m_s, mx);
        float al = __builtin_amdgcn_exp2f(m_s - mnew);
        m_s = mnew;
        float rs = 0.f;
#pragma unroll
        for (int nt = 0; nt < 4; nt++)
#pragma unroll
            for (int r = 0; r < 4; r++) {
                s[nt][r] = __builtin_amdgcn_exp2f(s[nt][r] - m_s);
                rs += s[nt][r];
            }
        rs += __shfl_xor(rs, 16);
        rs += __shfl_xor(rs, 32);
        l_s = l_s * al + rs;

        float alr[4];
#pragma unroll
        for (int r = 0; r < 4; r++) alr[r] = __shfl(al, quad * 4 + r, 16);
#pragma unroll
        for (int nt = 0; nt < 4; nt++)
#pragma unroll
            for (int r = 0; r < 4; r++) o[nt][r] *= alr[r];

#pragma unroll
        for (int nt = 0; nt < 4; nt++) {
            short4v pk;
#pragma unroll
            for (int r = 0; r < 4; r++) pk[r] = (short)f2bf(s[nt][r]);
            *(short4v*)&ppriv[lo * PSTR + nt * 16 + quad * 4] = pk;
        }
        short8 pf0 = *(const short8*)&ppriv[lo * PSTR + quad * 8];
        short8 pf1 = *(const short8*)&ppriv[lo * PSTR + 32 + quad * 8];

#pragma unroll
        for (int nt = 0; nt < 4; nt++) {
            const int row = nt * 16 + lo;
            short8 vf0 = *(const short8*)&vt_lds[row * 64 + ((quad ^ (row & 7)) * 8)];
            short8 vf1 = *(const short8*)&vt_lds[row * 64 + (((4 + quad) ^ (row & 7)) * 8)];
            o[nt] = __builtin_amdgcn_mfma_f32_16x16x32_bf16(pf0, vf0, o[nt], 0, 0, 0);
            o[nt] = __builtin_amdgcn_mfma_f32_16x16x32_bf16(pf1, vf1, o[nt], 0, 0, 0);
        }
        __syncthreads();
    }

    const int b = bh >> 4, h = bh & 15;
    float inv[4];
#pragma unroll
    for (int r = 0; r < 4; r++) inv[r] = 1.0f / __shfl(l_s, quad * 4 + r, 16);
#pragma unroll
    for (int nt = 0; nt < 4; nt++)
#pragma unroll
        for (int r = 0; r < 4; r++) {
            int srow = q0 + w * 16 + quad * 4 + r;
            attn_out[((size_t)b * SQL + srow) * HH + h * HDD + nt * 16 + lo] =
                f2bf(o[nt][r] * inv[r]);
        }
}

// ---------------- LayerNorm ----------------
__global__ __launch_bounds__(256) void ln_kernel(const float* __restrict__ x,
                                                 const float* __restrict__ g,
                                                 const float* __restrict__ bb,
                                                 float* __restrict__ out)
{
    const int row = blockIdx.x;
    const int t = threadIdx.x;
    const float* xr = x + (size_t)row * HH;
    float4 v = *(const float4*)(xr + t * 4);
    float s1 = v.x + v.y + v.z + v.w;
    float s2 = v.x * v.x + v.y * v.y + v.z * v.z + v.w * v.w;
#pragma unroll
    for (int off = 32; off; off >>= 1) { s1 += __shfl_xor(s1, off); s2 += __shfl_xor(s2, off); }
    __shared__ float red[8];
    if ((t & 63) == 0) { red[(t >> 6) * 2] = s1; red[(t >> 6) * 2 + 1] = s2; }
    __syncthreads();
    s1 = red[0] + red[2] + red[4] + red[6];
    s2 = red[1] + red[3] + red[5] + red[7];
    float mu = s1 * (1.0f / HH);
    float var = s2 * (1.0f / HH) - mu * mu;
    float rstd = rsqrtf(var + 1e-5f);
    float4 gg = *(const float4*)(g + t * 4);
    float4 b4 = *(const float4*)(bb + t * 4);
    float4 o;
    o.x = (v.x - mu) * rstd * gg.x + b4.x;
    o.y = (v.y - mu) * rstd * gg.y + b4.y;
    o.z = (v.z - mu) * rstd * gg.z + b4.z;
    o.w = (v.w - mu) * rstd * gg.w + b4.w;
    *(float4*)(out + (size_t)row * HH + t * 4) = o;
}

extern "C" void kernel_launch(void* const* d_in, const int* in_sizes, int n_in,
                              void* d_out, int out_size, void* d_ws, size_t ws_size,
                              hipStream_t stream)
{
    const float* query = (const float*)d_in[0];
    const float* key   = (const float*)d_in[1];
    const float* value = (const float*)d_in[2];
    // d_in[3] = causal_mask (tril by construction; causality hardcoded)
    const float* Wq = (const float*)d_in[4];
    const float* bq = (const float*)d_in[5];
    const float* Wk = (const float*)d_in[6];
    const float* bk = (const float*)d_in[7];
    const float* Wv = (const float*)d_in[8];
    const float* bv = (const float*)d_in[9];
    const float* Wo = (const float*)d_in[10];
    const float* bo = (const float*)d_in[11];
    const float* ln_g = (const float*)d_in[12];
    const float* ln_b = (const float*)d_in[13];
    float* out = (float*)d_out;

    char* wp = (char*)d_ws;
    auto alloc = [&](size_t bytes) { void* p = (void*)wp; wp += (bytes + 255) & ~(size_t)255; return p; };
    const int nW = HH * HH;    // 1M
    const int nX = MM * HH;    // 4M
    u16* wqb = (u16*)alloc((size_t)nW * 2);
    u16* wkb = (u16*)alloc((size_t)nW * 2);
    u16* wvb = (u16*)alloc((size_t)nW * 2);
    u16* wob = (u16*)alloc((size_t)nW * 2);
    u16* xq  = (u16*)alloc((size_t)nX * 2);
    u16* xk  = (u16*)alloc((size_t)nX * 2);
    u16* xv  = (u16*)alloc((size_t)nX * 2);
    u16* qbuf = (u16*)alloc((size_t)nX * 2);   // [b][h][s][d]
    u16* kbuf = (u16*)alloc((size_t)nX * 2);   // [b][h][s][d]
    u16* vbuf = (u16*)alloc((size_t)nX * 2);   // V^T [b][h][d][s]
    u16* attnb = (u16*)alloc((size_t)nX * 2);  // [b][s][h*d]
    float* projf = (float*)alloc((size_t)nX * 4);

    cvt_all_kernel<<<16384, 256, 0, stream>>>(query, key, value, Wq, Wk, Wv, Wo,
                                              xq, xk, xv, wqb, wkb, wvb, wob);

    proj_kernel<<<dim3(32, 8, 3), 256, 0, stream>>>(
        xq, xk, xv, wqb, wkb, wvb, bq, bk, bv, qbuf, kbuf, vbuf);

    attn_kernel<<<1024, 256, 0, stream>>>(qbuf, kbuf, vbuf, attnb);

    outproj_kernel<<<dim3(64, 8), 256, 0, stream>>>(attnb, wob, bo, query, projf);

    ln_kernel<<<MM, 256, 0, stream>>>(projf, ln_g, ln_b, out);
}